// Round 1
// baseline (416.312 us; speedup 1.0000x reference)
//
#include <hip/hip_runtime.h>
#include <math.h>

// Problem constants
#define B_    32
#define C3_   1024
#define C4_   2048
#define C_    3072
#define P_    784      // 28*28
#define L_    9
#define NG_   25088    // B_*P_
#define A_    312
#define NC_   200

// d_out layout (floats): attr(32x312), class(32x200), maps(32x9x784), af(32x3072x9)
#define ATTR_OFF  0
#define CLASS_OFF 9984
#define MAPS_OFF  16384
#define AF_OFF    242176

// workspace layout (floats)
#define ASQ_OFF  0
#define MF_OFF   16
#define PART_OFF (16 + B_*C_)   // 98320
#define NSLAB    10             // 8 slabs x 256 l4-ch, 2 slabs x 512 l3-ch

// ---------------------------------------------------------------- K0: a_sq[l]
__global__ void k0_asq(const float* __restrict__ conv_w, float* __restrict__ asq) {
    __shared__ float red[256];
    int t = threadIdx.x;
    for (int l = 0; l < L_; ++l) {
        float s = 0.f;
        for (int c = t; c < C_; c += 256) s += conv_w[l * C_ + c];
        red[t] = s; __syncthreads();
        for (int o = 128; o > 0; o >>= 1) {
            if (t < o) red[t] += red[t + o];
            __syncthreads();
        }
        if (t == 0) asq[l] = red[0];
        __syncthreads();
    }
}

// --------------------------------------------------- K1: ab partials per slab
__global__ __launch_bounds__(256) void k1_ab(
        const float* __restrict__ l3, const float* __restrict__ l4,
        const float* __restrict__ conv_w, float* __restrict__ part) {
    int g = blockIdx.x * 256 + threadIdx.x;       // 0..25087
    int b = g / P_;
    int p = g % P_;
    float ab[9];
#pragma unroll
    for (int l = 0; l < 9; ++l) ab[l] = 0.f;

    int slab = blockIdx.y;
    if (slab < 8) {
        // l4 (bilinear-upsampled) channels [slab*256, slab*256+256)
        int c0 = slab * 256;
        int y = p / 28, xo = p % 28;
        float sy = 0.5f * y - 0.25f, sx = 0.5f * xo - 0.25f;
        float fyf = floorf(sy), fxf = floorf(sx);
        float fy = sy - fyf, fx = sx - fxf;
        int y0 = max(0, (int)fyf), y1 = min(13, (int)fyf + 1);
        int x0 = max(0, (int)fxf), x1 = min(13, (int)fxf + 1);
        int o00 = y0 * 14 + x0, o01 = y0 * 14 + x1;
        int o10 = y1 * 14 + x0, o11 = y1 * 14 + x1;
        float w00 = (1.f - fy) * (1.f - fx), w01 = (1.f - fy) * fx;
        float w10 = fy * (1.f - fx),         w11 = fy * fx;
        const float* pl = l4 + ((size_t)b * C4_ + c0) * 196;
        for (int i = 0; i < 256; i += 4) {
            float v[4];
#pragma unroll
            for (int k = 0; k < 4; ++k) {
                v[k] = w00 * pl[o00] + w01 * pl[o01] + w10 * pl[o10] + w11 * pl[o11];
                pl += 196;
            }
#pragma unroll
            for (int l = 0; l < 9; ++l) {
                const float4 wq = *(const float4*)(conv_w + l * C_ + c0 + i);
                ab[l] = fmaf(wq.x, v[0], ab[l]);
                ab[l] = fmaf(wq.y, v[1], ab[l]);
                ab[l] = fmaf(wq.z, v[2], ab[l]);
                ab[l] = fmaf(wq.w, v[3], ab[l]);
            }
        }
    } else {
        // l3 channels [2048 + (slab-8)*512, ... +512)
        int c0 = C4_ + (slab - 8) * 512;
        const float* xp = l3 + ((size_t)b * C3_ + (c0 - C4_)) * P_ + p;
        for (int i = 0; i < 512; i += 4) {
            float v[4];
#pragma unroll
            for (int k = 0; k < 4; ++k) { v[k] = *xp; xp += P_; }
#pragma unroll
            for (int l = 0; l < 9; ++l) {
                const float4 wq = *(const float4*)(conv_w + l * C_ + c0 + i);
                ab[l] = fmaf(wq.x, v[0], ab[l]);
                ab[l] = fmaf(wq.y, v[1], ab[l]);
                ab[l] = fmaf(wq.z, v[2], ab[l]);
                ab[l] = fmaf(wq.w, v[3], ab[l]);
            }
        }
    }
#pragma unroll
    for (int l = 0; l < 9; ++l)
        part[(size_t)(slab * 9 + l) * NG_ + g] = ab[l];
}

// ------------------------------------------- K1b: slab-reduce + softmax(maps)
__global__ void k1b_softmax(const float* __restrict__ part,
                            const float* __restrict__ asq,
                            float* __restrict__ out_maps) {
    int g = blockIdx.x * 256 + threadIdx.x;
    int b = g / P_, p = g % P_;
    float v[9];
#pragma unroll
    for (int l = 0; l < 9; ++l) {
        float s = 0.f;
        for (int sl = 0; sl < NSLAB; ++sl)
            s += part[(size_t)(sl * 9 + l) * NG_ + g];
        v[l] = 2.f * s - asq[l];    // b_sq cancels in softmax over l
    }
    float m = v[0];
#pragma unroll
    for (int l = 1; l < 9; ++l) m = fmaxf(m, v[l]);
    float sum = 0.f;
#pragma unroll
    for (int l = 0; l < 9; ++l) { v[l] = expf(v[l] - m); sum += v[l]; }
    float inv = 1.f / sum;
#pragma unroll
    for (int l = 0; l < 9; ++l)
        out_maps[(size_t)b * (L_ * P_) + l * P_ + p] = v[l] * inv;
}

// --------------------------- K2: all_features (+ fused mean_features into ws)
__global__ __launch_bounds__(256) void k2_af(
        const float* __restrict__ l3, const float* __restrict__ l4,
        const float* __restrict__ modulation,
        const float* __restrict__ maps_g,
        float* __restrict__ out_af, float* __restrict__ mf) {
    __shared__ float  maps_s[L_ * P_];   // 28224 B
    __shared__ int4   off_s[P_];         // 12544 B
    __shared__ float4 wt_s[P_];          // 12544 B
    int b = blockIdx.x / 24;
    int grp = blockIdx.x % 24;           // 24 groups x 128 channels
    int t = threadIdx.x;

    for (int p = t; p < P_; p += 256) {
        int y = p / 28, xo = p % 28;
        float sy = 0.5f * y - 0.25f, sx = 0.5f * xo - 0.25f;
        float fyf = floorf(sy), fxf = floorf(sx);
        float fy = sy - fyf, fx = sx - fxf;
        int y0 = max(0, (int)fyf), y1 = min(13, (int)fyf + 1);
        int x0 = max(0, (int)fxf), x1 = min(13, (int)fxf + 1);
        off_s[p] = make_int4(y0 * 14 + x0, y0 * 14 + x1, y1 * 14 + x0, y1 * 14 + x1);
        wt_s[p] = make_float4((1.f - fy) * (1.f - fx), (1.f - fy) * fx,
                              fy * (1.f - fx), fy * fx);
    }
    for (int i = t; i < L_ * P_; i += 256)
        maps_s[i] = maps_g[(size_t)b * (L_ * P_) + i];
    __syncthreads();

    int wave = t >> 6, lane = t & 63;
    int cbase = grp * 128 + wave * 32;   // wave owns 32 channels

    for (int cb = 0; cb < 32; cb += 8) {
        int c = cbase + cb;
        float acc[8][9];
#pragma unroll
        for (int k = 0; k < 8; ++k)
#pragma unroll
            for (int l = 0; l < 9; ++l) acc[k][l] = 0.f;

        if (c < C4_) {
            const float* plane = l4 + ((size_t)b * C4_ + c) * 196;
            for (int chunk = 0; chunk < 13; ++chunk) {
                int p = chunk * 64 + lane;
                if (p < P_) {
                    float m[9];
#pragma unroll
                    for (int l = 0; l < 9; ++l) m[l] = maps_s[l * P_ + p];
                    int4 o = off_s[p]; float4 wt = wt_s[p];
#pragma unroll
                    for (int k = 0; k < 8; ++k) {
                        const float* pk = plane + k * 196;
                        float v = wt.x * pk[o.x] + wt.y * pk[o.y]
                                + wt.z * pk[o.z] + wt.w * pk[o.w];
#pragma unroll
                        for (int l = 0; l < 9; ++l)
                            acc[k][l] = fmaf(v, m[l], acc[k][l]);
                    }
                }
            }
        } else {
            const float* row = l3 + ((size_t)b * C3_ + (c - C4_)) * P_;
            for (int chunk = 0; chunk < 13; ++chunk) {
                int p = chunk * 64 + lane;
                if (p < P_) {
                    float m[9];
#pragma unroll
                    for (int l = 0; l < 9; ++l) m[l] = maps_s[l * P_ + p];
#pragma unroll
                    for (int k = 0; k < 8; ++k) {
                        float v = row[(size_t)k * P_ + p];
#pragma unroll
                        for (int l = 0; l < 9; ++l)
                            acc[k][l] = fmaf(v, m[l], acc[k][l]);
                    }
                }
            }
        }
#pragma unroll
        for (int k = 0; k < 8; ++k) {
            float red[9];
#pragma unroll
            for (int l = 0; l < 9; ++l) {
                float r = acc[k][l];
                r += __shfl_xor(r, 1);
                r += __shfl_xor(r, 2);
                r += __shfl_xor(r, 4);
                r += __shfl_xor(r, 8);
                r += __shfl_xor(r, 16);
                r += __shfl_xor(r, 32);
                red[l] = r;
            }
            if (lane == 0) {
                int cc = c + k;
                float s = 0.f;
#pragma unroll
                for (int l = 0; l < 9; ++l) {
                    float af = red[l] * (1.f / 784.f);
                    out_af[((size_t)b * C_ + cc) * 9 + l] = af;
                    if (l < 8) s = fmaf(af, modulation[cc * 9 + l], s);
                }
                mf[(size_t)b * C_ + cc] = s * 0.125f;
            }
        }
    }
}

// -------------------------------------------------- K3: attr = mf @ attr_w.T
__global__ __launch_bounds__(256) void k3_attr(
        const float* __restrict__ mf, const float* __restrict__ attr_w,
        const float* __restrict__ attr_b, float* __restrict__ out_attr) {
    int idx = blockIdx.x * 4 + (threadIdx.x >> 6);   // idx = b*312 + a
    int lane = threadIdx.x & 63;
    int b = idx / A_, a = idx % A_;
    const float4* wr = (const float4*)(attr_w + (size_t)a * C_);
    const float4* mr = (const float4*)(mf + (size_t)b * C_);
    float acc = 0.f;
    for (int j = lane; j < C_ / 4; j += 64) {
        float4 w = wr[j], m = mr[j];
        acc += w.x * m.x + w.y * m.y + w.z * m.z + w.w * m.w;
    }
    acc += __shfl_xor(acc, 1);  acc += __shfl_xor(acc, 2);
    acc += __shfl_xor(acc, 4);  acc += __shfl_xor(acc, 8);
    acc += __shfl_xor(acc, 16); acc += __shfl_xor(acc, 32);
    if (lane == 0) out_attr[idx] = acc + attr_b[a];
}

// ---------------------------------------------- K4: class = attr @ class_w.T
__global__ __launch_bounds__(256) void k4_class(
        const float* __restrict__ attr, const float* __restrict__ class_w,
        float* __restrict__ out_class) {
    int idx = blockIdx.x * 4 + (threadIdx.x >> 6);   // idx = b*200 + n
    int lane = threadIdx.x & 63;
    int b = idx / NC_, n = idx % NC_;
    float acc = 0.f;
    for (int a = lane; a < A_; a += 64)
        acc += attr[b * A_ + a] * class_w[n * A_ + a];
    acc += __shfl_xor(acc, 1);  acc += __shfl_xor(acc, 2);
    acc += __shfl_xor(acc, 4);  acc += __shfl_xor(acc, 8);
    acc += __shfl_xor(acc, 16); acc += __shfl_xor(acc, 32);
    if (lane == 0) out_class[idx] = acc;
}

extern "C" void kernel_launch(void* const* d_in, const int* in_sizes, int n_in,
                              void* d_out, int out_size, void* d_ws, size_t ws_size,
                              hipStream_t stream) {
    (void)in_sizes; (void)n_in; (void)out_size; (void)ws_size;
    const float* l3         = (const float*)d_in[0];
    const float* l4         = (const float*)d_in[1];
    const float* conv_w     = (const float*)d_in[2];
    const float* modulation = (const float*)d_in[3];
    const float* attr_w     = (const float*)d_in[4];
    const float* attr_b     = (const float*)d_in[5];
    const float* class_w    = (const float*)d_in[6];
    float* out = (float*)d_out;
    float* ws  = (float*)d_ws;
    float* asq  = ws + ASQ_OFF;
    float* mf   = ws + MF_OFF;
    float* part = ws + PART_OFF;

    k0_asq<<<1, 256, 0, stream>>>(conv_w, asq);
    k1_ab<<<dim3(98, NSLAB), 256, 0, stream>>>(l3, l4, conv_w, part);
    k1b_softmax<<<98, 256, 0, stream>>>(part, asq, out + MAPS_OFF);
    k2_af<<<768, 256, 0, stream>>>(l3, l4, modulation, out + MAPS_OFF,
                                   out + AF_OFF, mf);
    k3_attr<<<(B_ * A_) / 4, 256, 0, stream>>>(mf, attr_w, attr_b, out + ATTR_OFF);
    k4_class<<<(B_ * NC_) / 4, 256, 0, stream>>>(out + ATTR_OFF, class_w,
                                                 out + CLASS_OFF);
}

// Round 2
// 317.215 us; speedup vs baseline: 1.3124x; 1.3124x over previous
//
#include <hip/hip_runtime.h>
#include <math.h>

// Problem constants
#define B_    32
#define C3_   1024
#define C4_   2048
#define C_    3072
#define P_    784      // 28*28
#define Q_    196      // 14*14
#define L_    9
#define NG_   25088    // B_*P_
#define A_    312
#define NC_   200

// d_out layout (floats): attr(32x312), class(32x200), maps(32x9x784), af(32x3072x9)
#define ATTR_OFF  0
#define CLASS_OFF 9984
#define MAPS_OFF  16384
#define AF_OFF    242176

// workspace layout (floats)
#define ASQ_OFF  0
#define MF_OFF   16
#define PART3_OFF 98320                    // 4 slabs x 9 x NG_   = 903168
#define Y4P_OFF   1001488                  // 32 x 8 x 9 x 196    = 451584
#define Y_OFF     1453072                  // 32 x 9 x 196        = 56448
#define MP_OFF    1509520                  // 32 x 9 x 196        = 56448
// total 1565968 floats = 6.3 MB

// ============================================================= K_A (fused)
// blocks [0,392): l3 ab-partials (98 pixel-blocks x 4 channel-slabs of 256)
// blocks [392,648): l4 channel contraction at 14x14: Y4p[b,grp,l,q]
// block 648: a_sq
__global__ __launch_bounds__(256) void kA(
        const float* __restrict__ l3, const float* __restrict__ l4,
        const float* __restrict__ conv_w,
        float* __restrict__ part3, float* __restrict__ y4p,
        float* __restrict__ asq) {
    int bid = blockIdx.x;
    int t = threadIdx.x;
    if (bid < 392) {
        // ---- l3 partials: ab3[l,g] for channels [slab*256, slab*256+256)
        int g = (bid % 98) * 256 + t;         // 0..25087
        int slab = bid / 98;                  // 0..3
        int b = g / P_, p = g % P_;
        int c0 = slab * 256;                  // l3-local channel base
        const float* xp = l3 + ((size_t)b * C3_ + c0) * P_ + p;
        float ab[9];
#pragma unroll
        for (int l = 0; l < 9; ++l) ab[l] = 0.f;
        for (int i = 0; i < 256; i += 4) {
            float v0 = xp[0], v1 = xp[P_], v2 = xp[2 * P_], v3 = xp[3 * P_];
            xp += 4 * P_;
#pragma unroll
            for (int l = 0; l < 9; ++l) {
                const float4 wq = *(const float4*)(conv_w + l * C_ + C4_ + c0 + i);
                ab[l] = fmaf(wq.x, v0, ab[l]);
                ab[l] = fmaf(wq.y, v1, ab[l]);
                ab[l] = fmaf(wq.z, v2, ab[l]);
                ab[l] = fmaf(wq.w, v3, ab[l]);
            }
        }
#pragma unroll
        for (int l = 0; l < 9; ++l)
            part3[(size_t)(slab * 9 + l) * NG_ + g] = ab[l];
    } else if (bid < 648) {
        // ---- l4 contraction at source resolution: y4p[(b*8+grp)*9+l][q]
        int idx = bid - 392;
        int b = idx >> 3, grp = idx & 7;
        int c0 = grp * 256;
        if (t < Q_) {
            int q = t;
            const float* base = l4 + ((size_t)b * C4_ + c0) * Q_ + q;
            float acc[9];
#pragma unroll
            for (int l = 0; l < 9; ++l) acc[l] = 0.f;
            for (int c = 0; c < 256; c += 4) {
                float v0 = base[(size_t)(c + 0) * Q_];
                float v1 = base[(size_t)(c + 1) * Q_];
                float v2 = base[(size_t)(c + 2) * Q_];
                float v3 = base[(size_t)(c + 3) * Q_];
#pragma unroll
                for (int l = 0; l < 9; ++l) {
                    const float4 wq = *(const float4*)(conv_w + l * C_ + c0 + c);
                    acc[l] = fmaf(wq.x, v0, acc[l]);
                    acc[l] = fmaf(wq.y, v1, acc[l]);
                    acc[l] = fmaf(wq.z, v2, acc[l]);
                    acc[l] = fmaf(wq.w, v3, acc[l]);
                }
            }
#pragma unroll
            for (int l = 0; l < 9; ++l)
                y4p[(size_t)((b * 8 + grp) * 9 + l) * Q_ + q] = acc[l];
        }
    } else {
        // ---- a_sq[l] = sum_c w[l,c]
        __shared__ float red[256];
        for (int l = 0; l < L_; ++l) {
            float s = 0.f;
            for (int c = t; c < C_; c += 256) s += conv_w[l * C_ + c];
            red[t] = s; __syncthreads();
            for (int o = 128; o > 0; o >>= 1) {
                if (t < o) red[t] += red[t + o];
                __syncthreads();
            }
            if (t == 0) asq[l] = red[0];
            __syncthreads();
        }
    }
}

// ================================================= K_B: reduce y4p -> Y[b,l,q]
__global__ __launch_bounds__(256) void kB(const float* __restrict__ y4p,
                                          float* __restrict__ Y) {
    int tid = blockIdx.x * 256 + threadIdx.x;
    if (tid >= 32 * 9 * Q_) return;
    int b = tid / (9 * Q_);
    int r = tid % (9 * Q_);       // l*196 + q
    float s = 0.f;
#pragma unroll
    for (int grp = 0; grp < 8; ++grp)
        s += y4p[(size_t)(b * 8 + grp) * (9 * Q_) + r];
    Y[(size_t)b * (9 * Q_) + r] = s;
}

// =================== K_C: assemble ab (upsample Y + l3 partials) + softmax
__global__ __launch_bounds__(256) void kC(const float* __restrict__ part3,
                                          const float* __restrict__ Y,
                                          const float* __restrict__ asq,
                                          float* __restrict__ out_maps) {
    int g = blockIdx.x * 256 + threadIdx.x;   // 0..25087
    int b = g / P_, p = g % P_;
    int yy = p / 28, xx = p % 28;
    float sy = 0.5f * yy - 0.25f, sx = 0.5f * xx - 0.25f;
    float fyf = floorf(sy), fxf = floorf(sx);
    float fy = sy - fyf, fx = sx - fxf;
    int ya = max(0, (int)fyf), yb = min(13, (int)fyf + 1);
    int xa = max(0, (int)fxf), xb = min(13, (int)fxf + 1);
    int o00 = ya * 14 + xa, o01 = ya * 14 + xb;
    int o10 = yb * 14 + xa, o11 = yb * 14 + xb;
    float w00 = (1.f - fy) * (1.f - fx), w01 = (1.f - fy) * fx;
    float w10 = fy * (1.f - fx),         w11 = fy * fx;
    const float* Yb = Y + (size_t)b * (9 * Q_);
    float v[9];
#pragma unroll
    for (int l = 0; l < 9; ++l) {
        const float* Yl = Yb + l * Q_;
        float ab4 = w00 * Yl[o00] + w01 * Yl[o01] + w10 * Yl[o10] + w11 * Yl[o11];
        float ab3 = 0.f;
#pragma unroll
        for (int sl = 0; sl < 4; ++sl)
            ab3 += part3[(size_t)(sl * 9 + l) * NG_ + g];
        v[l] = 2.f * (ab4 + ab3) - asq[l];    // b_sq cancels in softmax over l
    }
    float m = v[0];
#pragma unroll
    for (int l = 1; l < 9; ++l) m = fmaxf(m, v[l]);
    float sum = 0.f;
#pragma unroll
    for (int l = 0; l < 9; ++l) { v[l] = expf(v[l] - m); sum += v[l]; }
    float inv = 1.f / sum;
#pragma unroll
    for (int l = 0; l < 9; ++l)
        out_maps[(size_t)b * (L_ * P_) + l * P_ + p] = v[l] * inv;
}

// ============== K_D: adjoint bilinear downsample of maps -> Mp[b,l,q]
__device__ __forceinline__ int adj_taps(int q, int* ys, float* wy) {
    if (q == 0)  { ys[0] = 0;  wy[0] = 1.00f; ys[1] = 1;  wy[1] = 0.75f;
                   ys[2] = 2;  wy[2] = 0.25f; return 3; }
    if (q == 13) { ys[0] = 25; wy[0] = 0.25f; ys[1] = 26; wy[1] = 0.75f;
                   ys[2] = 27; wy[2] = 1.00f; return 3; }
    ys[0] = 2 * q - 1; wy[0] = 0.25f;
    ys[1] = 2 * q;     wy[1] = 0.75f;
    ys[2] = 2 * q + 1; wy[2] = 0.75f;
    ys[3] = 2 * q + 2; wy[3] = 0.25f;
    return 4;
}

__global__ __launch_bounds__(256) void kD(const float* __restrict__ maps,
                                          float* __restrict__ Mp) {
    int tid = blockIdx.x * 256 + threadIdx.x;
    if (tid >= 32 * 9 * Q_) return;
    int b = tid / (9 * Q_);
    int r = tid % (9 * Q_);
    int l = r / Q_, q = r % Q_;
    int qy = q / 14, qx = q % 14;
    int ys[4], xs[4]; float wy[4], wx[4];
    int ny = adj_taps(qy, ys, wy);
    int nx = adj_taps(qx, xs, wx);
    const float* mrow = maps + (size_t)b * (L_ * P_) + l * P_;
    float s = 0.f;
    for (int i = 0; i < ny; ++i) {
        float rs = 0.f;
        for (int j = 0; j < nx; ++j)
            rs = fmaf(wx[j], mrow[ys[i] * 28 + xs[j]], rs);
        s = fmaf(wy[i], rs, s);
    }
    Mp[(size_t)b * (9 * Q_) + r] = s;
}

// ===================== K_E: all_features + fused mean_features
// blocks [0,128): l3 half   (b, grp of 256 ch) : dot over 784 px with maps
// blocks [128,384): l4 half (b, grp of 256 ch) : dot over 196 px with Mp
__global__ __launch_bounds__(256) void kE(
        const float* __restrict__ l3, const float* __restrict__ l4,
        const float* __restrict__ maps, const float* __restrict__ Mp,
        const float* __restrict__ modulation,
        float* __restrict__ out_af, float* __restrict__ mf) {
    int bid = blockIdx.x;
    int t = threadIdx.x;
    float acc[9];
#pragma unroll
    for (int l = 0; l < 9; ++l) acc[l] = 0.f;
    int b, gc;
    if (bid < 128) {
        b = bid >> 2;
        int c3 = (bid & 3) * 256 + t;          // l3-local channel
        gc = C4_ + c3;                          // global channel
        const float* row = l3 + ((size_t)b * C3_ + c3) * P_;
        const float* mb = maps + (size_t)b * (L_ * P_);
        for (int p = 0; p < P_; p += 4) {
            const float4 xv = *(const float4*)(row + p);
#pragma unroll
            for (int l = 0; l < 9; ++l) {
                const float4 mv = *(const float4*)(mb + l * P_ + p);  // uniform -> s_load
                acc[l] = fmaf(xv.x, mv.x, acc[l]);
                acc[l] = fmaf(xv.y, mv.y, acc[l]);
                acc[l] = fmaf(xv.z, mv.z, acc[l]);
                acc[l] = fmaf(xv.w, mv.w, acc[l]);
            }
        }
    } else {
        int idx = bid - 128;
        b = idx >> 3;
        gc = (idx & 7) * 256 + t;               // l4 channel == global channel
        const float* plane = l4 + ((size_t)b * C4_ + gc) * Q_;
        const float* mpb = Mp + (size_t)b * (9 * Q_);
        for (int q = 0; q < Q_; q += 4) {
            const float4 xv = *(const float4*)(plane + q);
#pragma unroll
            for (int l = 0; l < 9; ++l) {
                const float4 mv = *(const float4*)(mpb + l * Q_ + q);  // uniform -> s_load
                acc[l] = fmaf(xv.x, mv.x, acc[l]);
                acc[l] = fmaf(xv.y, mv.y, acc[l]);
                acc[l] = fmaf(xv.z, mv.z, acc[l]);
                acc[l] = fmaf(xv.w, mv.w, acc[l]);
            }
        }
    }
    float s = 0.f;
#pragma unroll
    for (int l = 0; l < 9; ++l) {
        float af = acc[l] * (1.f / 784.f);
        out_af[((size_t)b * C_ + gc) * 9 + l] = af;
        if (l < 8) s = fmaf(af, modulation[gc * 9 + l], s);
    }
    mf[(size_t)b * C_ + gc] = s * 0.125f;
}

// -------------------------------------------------- K_F: attr = mf @ attr_w.T
__global__ __launch_bounds__(256) void kF(
        const float* __restrict__ mf, const float* __restrict__ attr_w,
        const float* __restrict__ attr_b, float* __restrict__ out_attr) {
    int idx = blockIdx.x * 4 + (threadIdx.x >> 6);   // idx = b*312 + a
    int lane = threadIdx.x & 63;
    int b = idx / A_, a = idx % A_;
    const float4* wr = (const float4*)(attr_w + (size_t)a * C_);
    const float4* mr = (const float4*)(mf + (size_t)b * C_);
    float acc = 0.f;
    for (int j = lane; j < C_ / 4; j += 64) {
        float4 w = wr[j], m = mr[j];
        acc += w.x * m.x + w.y * m.y + w.z * m.z + w.w * m.w;
    }
    acc += __shfl_xor(acc, 1);  acc += __shfl_xor(acc, 2);
    acc += __shfl_xor(acc, 4);  acc += __shfl_xor(acc, 8);
    acc += __shfl_xor(acc, 16); acc += __shfl_xor(acc, 32);
    if (lane == 0) out_attr[idx] = acc + attr_b[a];
}

// ---------------------------------------------- K_G: class = attr @ class_w.T
__global__ __launch_bounds__(256) void kG(
        const float* __restrict__ attr, const float* __restrict__ class_w,
        float* __restrict__ out_class) {
    int idx = blockIdx.x * 4 + (threadIdx.x >> 6);   // idx = b*200 + n
    int lane = threadIdx.x & 63;
    int b = idx / NC_, n = idx % NC_;
    float acc = 0.f;
    for (int a = lane; a < A_; a += 64)
        acc += attr[b * A_ + a] * class_w[n * A_ + a];
    acc += __shfl_xor(acc, 1);  acc += __shfl_xor(acc, 2);
    acc += __shfl_xor(acc, 4);  acc += __shfl_xor(acc, 8);
    acc += __shfl_xor(acc, 16); acc += __shfl_xor(acc, 32);
    if (lane == 0) out_class[idx] = acc;
}

extern "C" void kernel_launch(void* const* d_in, const int* in_sizes, int n_in,
                              void* d_out, int out_size, void* d_ws, size_t ws_size,
                              hipStream_t stream) {
    (void)in_sizes; (void)n_in; (void)out_size; (void)ws_size;
    const float* l3         = (const float*)d_in[0];
    const float* l4         = (const float*)d_in[1];
    const float* conv_w     = (const float*)d_in[2];
    const float* modulation = (const float*)d_in[3];
    const float* attr_w     = (const float*)d_in[4];
    const float* attr_b     = (const float*)d_in[5];
    const float* class_w    = (const float*)d_in[6];
    float* out = (float*)d_out;
    float* ws  = (float*)d_ws;
    float* asq   = ws + ASQ_OFF;
    float* mf    = ws + MF_OFF;
    float* part3 = ws + PART3_OFF;
    float* y4p   = ws + Y4P_OFF;
    float* Y     = ws + Y_OFF;
    float* Mp    = ws + MP_OFF;

    kA<<<649, 256, 0, stream>>>(l3, l4, conv_w, part3, y4p, asq);
    kB<<<221, 256, 0, stream>>>(y4p, Y);
    kC<<<98, 256, 0, stream>>>(part3, Y, asq, out + MAPS_OFF);
    kD<<<221, 256, 0, stream>>>(out + MAPS_OFF, Mp);
    kE<<<384, 256, 0, stream>>>(l3, l4, out + MAPS_OFF, Mp, modulation,
                                out + AF_OFF, mf);
    kF<<<(B_ * A_) / 4, 256, 0, stream>>>(mf, attr_w, attr_b, out + ATTR_OFF);
    kG<<<(B_ * NC_) / 4, 256, 0, stream>>>(out + ATTR_OFF, class_w,
                                           out + CLASS_OFF);
}

// Round 3
// 307.954 us; speedup vs baseline: 1.3519x; 1.0301x over previous
//
#include <hip/hip_runtime.h>
#include <math.h>

// Problem constants
#define B_    32
#define C3_   1024
#define C4_   2048
#define C_    3072
#define P_    784      // 28*28
#define Q_    196      // 14*14
#define L_    9
#define NG_   25088    // B_*P_
#define A_    312
#define NC_   200

// d_out layout (floats): attr(32x312), class(32x200), maps(32x9x784), af(32x3072x9)
#define ATTR_OFF  0
#define CLASS_OFF 9984
#define MAPS_OFF  16384
#define AF_OFF    242176

// workspace layout (floats)
#define ASQ_OFF   0
#define MF_OFF    16
#define PART3_OFF (16 + B_ * C_)                 // 98320 ; 8 slabs x 9 x NG_
#define Y4P_OFF   (PART3_OFF + 8 * 9 * NG_)      // 1904656 ; 32 x 16 x 9 x 196
#define Y_OFF     (Y4P_OFF + 32 * 16 * 9 * Q_)   // 2807824 ; 32 x 9 x 196
#define MP_OFF    (Y_OFF + 32 * 9 * Q_)          // 2864272 ; 32 x 9 x 196
// end: 2920720 floats = 11.7 MB

typedef __attribute__((ext_vector_type(8))) short bf16x8;
typedef __attribute__((ext_vector_type(4))) float f32x4;

__device__ __forceinline__ short f2bf(float f) {
    union { float f; unsigned u; } v; v.f = f;
    unsigned r = v.u + 0x7FFFu + ((v.u >> 16) & 1u);   // RNE
    return (short)(r >> 16);
}

// ============================================================= K_A (fused)
// blocks [0,784): l3 ab-partials (98 pixel-blocks x 8 slabs of 128 ch)
// blocks [784,1296): l4 contraction at 14x14 (32 b x 16 grps of 128 ch)
// block 1296: a_sq
__global__ __launch_bounds__(256) void kA(
        const float* __restrict__ l3, const float* __restrict__ l4,
        const float* __restrict__ conv_w,
        float* __restrict__ part3, float* __restrict__ y4p,
        float* __restrict__ asq) {
    int bid = blockIdx.x;
    int t = threadIdx.x;
    if (bid < 784) {
        int g = (bid % 98) * 256 + t;          // 0..25087
        int slab = bid / 98;                   // 0..7
        int b = g / P_, p = g % P_;
        int c0 = slab * 128;                   // l3-local channel base
        const float* xp = l3 + ((size_t)b * C3_ + c0) * P_ + p;
        float ab[9];
#pragma unroll
        for (int l = 0; l < 9; ++l) ab[l] = 0.f;
        for (int i = 0; i < 128; i += 8) {
            float v[8];
#pragma unroll
            for (int k = 0; k < 8; ++k) v[k] = xp[(size_t)k * P_];
            xp += (size_t)8 * P_;
#pragma unroll
            for (int l = 0; l < 9; ++l) {
                const float4 w0 = *(const float4*)(conv_w + l * C_ + C4_ + c0 + i);
                const float4 w1 = *(const float4*)(conv_w + l * C_ + C4_ + c0 + i + 4);
                ab[l] = fmaf(w0.x, v[0], ab[l]);
                ab[l] = fmaf(w0.y, v[1], ab[l]);
                ab[l] = fmaf(w0.z, v[2], ab[l]);
                ab[l] = fmaf(w0.w, v[3], ab[l]);
                ab[l] = fmaf(w1.x, v[4], ab[l]);
                ab[l] = fmaf(w1.y, v[5], ab[l]);
                ab[l] = fmaf(w1.z, v[6], ab[l]);
                ab[l] = fmaf(w1.w, v[7], ab[l]);
            }
        }
#pragma unroll
        for (int l = 0; l < 9; ++l)
            part3[(size_t)(slab * 9 + l) * NG_ + g] = ab[l];
    } else if (bid < 1296) {
        int idx = bid - 784;
        int b = idx >> 4, grp = idx & 15;
        int c0 = grp * 128;
        if (t < Q_) {
            const float* base = l4 + ((size_t)b * C4_ + c0) * Q_ + t;
            float acc[9];
#pragma unroll
            for (int l = 0; l < 9; ++l) acc[l] = 0.f;
            for (int c = 0; c < 128; c += 8) {
                float v[8];
#pragma unroll
                for (int k = 0; k < 8; ++k) v[k] = base[(size_t)(c + k) * Q_];
#pragma unroll
                for (int l = 0; l < 9; ++l) {
                    const float4 w0 = *(const float4*)(conv_w + l * C_ + c0 + c);
                    const float4 w1 = *(const float4*)(conv_w + l * C_ + c0 + c + 4);
                    acc[l] = fmaf(w0.x, v[0], acc[l]);
                    acc[l] = fmaf(w0.y, v[1], acc[l]);
                    acc[l] = fmaf(w0.z, v[2], acc[l]);
                    acc[l] = fmaf(w0.w, v[3], acc[l]);
                    acc[l] = fmaf(w1.x, v[4], acc[l]);
                    acc[l] = fmaf(w1.y, v[5], acc[l]);
                    acc[l] = fmaf(w1.z, v[6], acc[l]);
                    acc[l] = fmaf(w1.w, v[7], acc[l]);
                }
            }
#pragma unroll
            for (int l = 0; l < 9; ++l)
                y4p[(size_t)((b * 16 + grp) * 9 + l) * Q_ + t] = acc[l];
        }
    } else {
        __shared__ float red[256];
        for (int l = 0; l < L_; ++l) {
            float s = 0.f;
            for (int c = t; c < C_; c += 256) s += conv_w[l * C_ + c];
            red[t] = s; __syncthreads();
            for (int o = 128; o > 0; o >>= 1) {
                if (t < o) red[t] += red[t + o];
                __syncthreads();
            }
            if (t == 0) asq[l] = red[0];
            __syncthreads();
        }
    }
}

// ================================================= K_B: reduce y4p -> Y[b,l,q]
__global__ __launch_bounds__(256) void kB(const float* __restrict__ y4p,
                                          float* __restrict__ Y) {
    int tid = blockIdx.x * 256 + threadIdx.x;
    if (tid >= 32 * 9 * Q_) return;
    int b = tid / (9 * Q_);
    int r = tid % (9 * Q_);
    float s = 0.f;
#pragma unroll
    for (int grp = 0; grp < 16; ++grp)
        s += y4p[(size_t)(b * 16 + grp) * (9 * Q_) + r];
    Y[(size_t)b * (9 * Q_) + r] = s;
}

// =================== K_C: assemble ab (upsample Y + l3 partials) + softmax
__global__ __launch_bounds__(256) void kC(const float* __restrict__ part3,
                                          const float* __restrict__ Y,
                                          const float* __restrict__ asq,
                                          float* __restrict__ out_maps) {
    int g = blockIdx.x * 256 + threadIdx.x;   // 0..25087
    int b = g / P_, p = g % P_;
    int yy = p / 28, xx = p % 28;
    float sy = 0.5f * yy - 0.25f, sx = 0.5f * xx - 0.25f;
    float fyf = floorf(sy), fxf = floorf(sx);
    float fy = sy - fyf, fx = sx - fxf;
    int ya = max(0, (int)fyf), yb = min(13, (int)fyf + 1);
    int xa = max(0, (int)fxf), xb = min(13, (int)fxf + 1);
    int o00 = ya * 14 + xa, o01 = ya * 14 + xb;
    int o10 = yb * 14 + xa, o11 = yb * 14 + xb;
    float w00 = (1.f - fy) * (1.f - fx), w01 = (1.f - fy) * fx;
    float w10 = fy * (1.f - fx),         w11 = fy * fx;
    const float* Yb = Y + (size_t)b * (9 * Q_);
    float v[9];
#pragma unroll
    for (int l = 0; l < 9; ++l) {
        const float* Yl = Yb + l * Q_;
        float ab4 = w00 * Yl[o00] + w01 * Yl[o01] + w10 * Yl[o10] + w11 * Yl[o11];
        float ab3 = 0.f;
#pragma unroll
        for (int sl = 0; sl < 8; ++sl)
            ab3 += part3[(size_t)(sl * 9 + l) * NG_ + g];
        v[l] = 2.f * (ab4 + ab3) - asq[l];    // b_sq cancels in softmax over l
    }
    float m = v[0];
#pragma unroll
    for (int l = 1; l < 9; ++l) m = fmaxf(m, v[l]);
    float sum = 0.f;
#pragma unroll
    for (int l = 0; l < 9; ++l) { v[l] = expf(v[l] - m); sum += v[l]; }
    float inv = 1.f / sum;
#pragma unroll
    for (int l = 0; l < 9; ++l)
        out_maps[(size_t)b * (L_ * P_) + l * P_ + p] = v[l] * inv;
}

// ============== K_D: adjoint bilinear downsample of maps -> Mp[b,l,q]
__device__ __forceinline__ int adj_taps(int q, int* ys, float* wy) {
    if (q == 0)  { ys[0] = 0;  wy[0] = 1.00f; ys[1] = 1;  wy[1] = 0.75f;
                   ys[2] = 2;  wy[2] = 0.25f; return 3; }
    if (q == 13) { ys[0] = 25; wy[0] = 0.25f; ys[1] = 26; wy[1] = 0.75f;
                   ys[2] = 27; wy[2] = 1.00f; return 3; }
    ys[0] = 2 * q - 1; wy[0] = 0.25f;
    ys[1] = 2 * q;     wy[1] = 0.75f;
    ys[2] = 2 * q + 1; wy[2] = 0.75f;
    ys[3] = 2 * q + 2; wy[3] = 0.25f;
    return 4;
}

__global__ __launch_bounds__(256) void kD(const float* __restrict__ maps,
                                          float* __restrict__ Mp) {
    int tid = blockIdx.x * 256 + threadIdx.x;
    if (tid >= 32 * 9 * Q_) return;
    int b = tid / (9 * Q_);
    int r = tid % (9 * Q_);
    int l = r / Q_, q = r % Q_;
    int qy = q / 14, qx = q % 14;
    int ys[4], xs[4]; float wy[4], wx[4];
    int ny = adj_taps(qy, ys, wy);
    int nx = adj_taps(qx, xs, wx);
    const float* mrow = maps + (size_t)b * (L_ * P_) + l * P_;
    float s = 0.f;
    for (int i = 0; i < ny; ++i) {
        float rs = 0.f;
        for (int j = 0; j < nx; ++j)
            rs = fmaf(wx[j], mrow[ys[i] * 28 + xs[j]], rs);
        s = fmaf(wy[i], rs, s);
    }
    Mp[(size_t)b * (9 * Q_) + r] = s;
}

// ===================== K_E: all_features via MFMA bf16
// blocks [0,512): l3 half (b, 4 c-tiles of 16)  K=784
// blocks [512,1536): l4 half (b, 4 c-tiles of 16) K=196 vs Mp
#define KP3 800
#define KP4 224
#define BROW 808   // LDS row stride in bf16 elems (16B-aligned, low bank aliasing)
__global__ __launch_bounds__(256) void kE(
        const float* __restrict__ l3, const float* __restrict__ l4,
        const float* __restrict__ maps, const float* __restrict__ Mp,
        float* __restrict__ out_af) {
    __shared__ short bs[16 * BROW];            // 25856 B
    int bid = blockIdx.x;
    int t = threadIdx.x;
    int wave = t >> 6, lane = t & 63;
    int row = lane & 15, quad = lane >> 4;

    int b, K, gcbase;
    const float* xbase;
    if (bid < 512) {
        b = bid >> 4;
        int c0 = (bid & 15) * 64 + wave * 16;  // l3-local tile base
        gcbase = C4_ + c0;
        K = 784;
        xbase = l3 + ((size_t)b * C3_ + c0) * P_;
        const float* src = maps + (size_t)b * (L_ * P_);
        for (int i = t; i < 9 * KP3; i += 256) {
            int l = i / KP3, k = i - l * KP3;
            float v = (k < 784) ? src[l * P_ + k] : 0.f;
            bs[l * BROW + k] = f2bf(v);
        }
    } else {
        int idx = bid - 512;
        b = idx >> 5;
        int c0 = (idx & 31) * 64 + wave * 16;  // l4 channel tile base
        gcbase = c0;
        K = 196;
        xbase = l4 + ((size_t)b * C4_ + c0) * Q_;
        const float* src = Mp + (size_t)b * (9 * Q_);
        for (int i = t; i < 9 * KP4; i += 256) {
            int l = i / KP4, k = i - l * KP4;
            float v = (k < 196) ? src[l * Q_ + k] : 0.f;
            bs[l * BROW + k] = f2bf(v);
        }
    }
    __syncthreads();

    const float* xrow = xbase + (size_t)row * K;   // A row: channel gcbase+row
    const short* brow = bs + row * BROW;           // B row: landmark l = row
    f32x4 acc = {0.f, 0.f, 0.f, 0.f};
    int kfull = (K / 32) * 32;                     // 768 / 192
#pragma unroll 4
    for (int k0 = 0; k0 < kfull; k0 += 32) {
        int ka = k0 + quad * 8;
        float4 xa = *(const float4*)(xrow + ka);
        float4 xb = *(const float4*)(xrow + ka + 4);
        bf16x8 a;
        a[0] = f2bf(xa.x); a[1] = f2bf(xa.y); a[2] = f2bf(xa.z); a[3] = f2bf(xa.w);
        a[4] = f2bf(xb.x); a[5] = f2bf(xb.y); a[6] = f2bf(xb.z); a[7] = f2bf(xb.w);
        bf16x8 bv = *(const bf16x8*)(brow + ka);
        acc = __builtin_amdgcn_mfma_f32_16x16x32_bf16(a, bv, acc, 0, 0, 0);
    }
    {   // tail K-step (masked A; B zero-padded in LDS)
        int ka = kfull + quad * 8;
        bf16x8 a;
#pragma unroll
        for (int j = 0; j < 8; ++j)
            a[j] = f2bf((ka + j < K) ? xrow[ka + j] : 0.f);
        bf16x8 bv = *(const bf16x8*)(brow + ka);
        acc = __builtin_amdgcn_mfma_f32_16x16x32_bf16(a, bv, acc, 0, 0, 0);
    }
    // D layout: col = lane&15 (= landmark l), row = quad*4 + reg (= channel)
    int l = row;
    if (l < 9) {
        size_t base = ((size_t)b * C_ + gcbase + quad * 4) * 9 + l;
#pragma unroll
        for (int r = 0; r < 4; ++r)
            out_af[base + (size_t)r * 9] = acc[r] * (1.f / 784.f);
    }
}

// ============ K_MF: mean_features (mean over l<8 of af*modulation)
__global__ __launch_bounds__(256) void kMF(const float* __restrict__ af,
                                           const float* __restrict__ mod,
                                           float* __restrict__ mf) {
    int i = blockIdx.x * 256 + threadIdx.x;   // b*C + c
    if (i >= B_ * C_) return;
    int c = i % C_;
    const float* a = af + (size_t)i * 9;
    const float* m = mod + (size_t)c * 9;
    float s = 0.f;
#pragma unroll
    for (int l = 0; l < 8; ++l) s = fmaf(a[l], m[l], s);
    mf[i] = s * 0.125f;
}

// -------------------------------------------------- K_F: attr = mf @ attr_w.T
__global__ __launch_bounds__(256) void kF(
        const float* __restrict__ mf, const float* __restrict__ attr_w,
        const float* __restrict__ attr_b, float* __restrict__ out_attr) {
    int idx = blockIdx.x * 4 + (threadIdx.x >> 6);   // idx = b*312 + a
    int lane = threadIdx.x & 63;
    int b = idx / A_, a = idx % A_;
    const float4* wr = (const float4*)(attr_w + (size_t)a * C_);
    const float4* mr = (const float4*)(mf + (size_t)b * C_);
    float acc = 0.f;
    for (int j = lane; j < C_ / 4; j += 64) {
        float4 w = wr[j], m = mr[j];
        acc += w.x * m.x + w.y * m.y + w.z * m.z + w.w * m.w;
    }
    acc += __shfl_xor(acc, 1);  acc += __shfl_xor(acc, 2);
    acc += __shfl_xor(acc, 4);  acc += __shfl_xor(acc, 8);
    acc += __shfl_xor(acc, 16); acc += __shfl_xor(acc, 32);
    if (lane == 0) out_attr[idx] = acc + attr_b[a];
}

// ---------------------------------------------- K_G: class = attr @ class_w.T
__global__ __launch_bounds__(256) void kG(
        const float* __restrict__ attr, const float* __restrict__ class_w,
        float* __restrict__ out_class) {
    int idx = blockIdx.x * 4 + (threadIdx.x >> 6);   // idx = b*200 + n
    int lane = threadIdx.x & 63;
    int b = idx / NC_, n = idx % NC_;
    float acc = 0.f;
    for (int a = lane; a < A_; a += 64)
        acc += attr[b * A_ + a] * class_w[n * A_ + a];
    acc += __shfl_xor(acc, 1);  acc += __shfl_xor(acc, 2);
    acc += __shfl_xor(acc, 4);  acc += __shfl_xor(acc, 8);
    acc += __shfl_xor(acc, 16); acc += __shfl_xor(acc, 32);
    if (lane == 0) out_class[idx] = acc;
}

extern "C" void kernel_launch(void* const* d_in, const int* in_sizes, int n_in,
                              void* d_out, int out_size, void* d_ws, size_t ws_size,
                              hipStream_t stream) {
    (void)in_sizes; (void)n_in; (void)out_size; (void)ws_size;
    const float* l3         = (const float*)d_in[0];
    const float* l4         = (const float*)d_in[1];
    const float* conv_w     = (const float*)d_in[2];
    const float* modulation = (const float*)d_in[3];
    const float* attr_w     = (const float*)d_in[4];
    const float* attr_b     = (const float*)d_in[5];
    const float* class_w    = (const float*)d_in[6];
    float* out = (float*)d_out;
    float* ws  = (float*)d_ws;
    float* asq   = ws + ASQ_OFF;
    float* mf    = ws + MF_OFF;
    float* part3 = ws + PART3_OFF;
    float* y4p   = ws + Y4P_OFF;
    float* Y     = ws + Y_OFF;
    float* Mp    = ws + MP_OFF;

    kA<<<1297, 256, 0, stream>>>(l3, l4, conv_w, part3, y4p, asq);
    kB<<<221, 256, 0, stream>>>(y4p, Y);
    kC<<<98, 256, 0, stream>>>(part3, Y, asq, out + MAPS_OFF);
    kD<<<221, 256, 0, stream>>>(out + MAPS_OFF, Mp);
    kE<<<1536, 256, 0, stream>>>(l3, l4, out + MAPS_OFF, Mp, out + AF_OFF);
    kMF<<<384, 256, 0, stream>>>(out + AF_OFF, modulation, mf);
    kF<<<(B_ * A_) / 4, 256, 0, stream>>>(mf, attr_w, attr_b, out + ATTR_OFF);
    kG<<<(B_ * NC_) / 4, 256, 0, stream>>>(out + ATTR_OFF, class_w,
                                           out + CLASS_OFF);
}